// Round 10
// baseline (560.530 us; speedup 1.0000x reference)
//
#include <hip/hip_runtime.h>
#include <hip/hip_fp16.h>
#include <math.h>
#include <string.h>

// ---------------- constants ----------------
constexpr int HDIM = 128;     // hidden width
constexpr int RB   = 136;     // fp16 row stride for hcat/z (272B = 17 x 16B)
constexpr int ZS   = 168;     // LDS z-tile stride (fp16)
constexpr float BN_INV = 0.99999500003749980f; // 1/sqrt(1+1e-5)

typedef _Float16 half8v __attribute__((ext_vector_type(8)));  // 8 fp16 (4 VGPR)
typedef __attribute__((ext_vector_type(4))) float float4v;    // MFMA accum

// packed fp16 ops on raw u32 pairs (VOP3P)
__device__ __forceinline__ unsigned pkmax(unsigned a, unsigned b) {
  unsigned r;
  asm volatile("v_pk_max_f16 %0, %1, %2" : "=v"(r) : "v"(a), "v"(b));
  return r;
}
__device__ __forceinline__ unsigned pkadd(unsigned a, unsigned b) {
  unsigned r;
  asm volatile("v_pk_add_f16 %0, %1, %2" : "=v"(r) : "v"(a), "v"(b));
  return r;
}

__device__ __forceinline__ float us2f(unsigned short u) { __half h; memcpy(&h, &u, 2); return __half2float(h); }
__device__ __forceinline__ unsigned short f2us(float f) {
  __half h = __float2half(f); unsigned short u; memcpy(&u, &h, 2); return u;
}

// monotone float<->uint encoding for atomic max on floats
__device__ __forceinline__ unsigned encf(float f) {
  unsigned u = __float_as_uint(f);
  return (u & 0x80000000u) ? ~u : (u | 0x80000000u);
}
__device__ __forceinline__ float decf(unsigned u) {
  return (u & 0x80000000u) ? __uint_as_float(u ^ 0x80000000u) : __uint_as_float(~u);
}

// ================= CSR build (bucket-local, LDS-atomic) =================
// 1) per-chunk bucket histogram (no global atomics, no memset needed)
__global__ __launch_bounds__(256) void k_bcnt(
    const int* __restrict__ ei, int* __restrict__ chunkHist, int E, int shift) {
  __shared__ int hb[256];
  const int tid = threadIdx.x;
  hb[tid] = 0;
  __syncthreads();
  const int base = blockIdx.x * 4096;
#pragma unroll
  for (int k = 0; k < 16; ++k) {
    int e = base + k * 256 + tid;
    if (e < E) atomicAdd(&hb[ei[E + e] >> shift], 1);
  }
  __syncthreads();
  chunkHist[blockIdx.x * 256 + tid] = hb[tid];
}

// 2) column-sum chunk histograms + exclusive scan -> bbase[0..nbkt], gcur
__global__ __launch_bounds__(256) void k_bscan(
    const int* __restrict__ chunkHist, int chunks,
    int* __restrict__ bbase, int* __restrict__ gcur, int nbkt, int E) {
  __shared__ int s[256];
  int tid = threadIdx.x;
  int v = 0;
  for (int c = 0; c < chunks; ++c) v += chunkHist[c * 256 + tid];
  s[tid] = v;
  __syncthreads();
  for (int off = 1; off < 256; off <<= 1) {
    int t = (tid >= off) ? s[tid - off] : 0;
    __syncthreads();
    s[tid] += t;
    __syncthreads();
  }
  if (tid < nbkt) {
    int e = s[tid] - v;
    bbase[tid] = e;
    gcur[tid] = e;
  }
  if (tid == 0) bbase[nbkt] = E;
}

// 3) phase A: block-local LDS counting-sort of 4096-edge chunks by bucket,
//    run-coalesced flush into per-bucket regions of `sorted` (u64 = dst<<32 | src)
__global__ __launch_bounds__(256) void k_bscatter(
    const int* __restrict__ ei, int* __restrict__ gcur,
    unsigned long long* __restrict__ sorted, int E, int shift, int nbkt) {
  __shared__ int hcnt[256];   // per-bucket count, then reused as cursor
  __shared__ int hstart[256]; // exclusive start within chunk
  __shared__ int gbase[256];  // global base for this block's run
  __shared__ unsigned long long sbuf[4096];  // 32 KB

  const int tid = threadIdx.x;
  const int base = blockIdx.x * 4096;
  const int validCount = min(4096, E - base);

  hcnt[tid] = 0;
  __syncthreads();

  int sArr[16], dArr[16];
#pragma unroll
  for (int k = 0; k < 16; ++k) {
    int e = base + k * 256 + tid;
    if (e < E) {
      sArr[k] = ei[e];
      dArr[k] = ei[E + e];
      atomicAdd(&hcnt[dArr[k] >> shift], 1);
    } else {
      sArr[k] = -1; dArr[k] = -1;
    }
  }
  __syncthreads();

  // exclusive scan of hcnt into hstart
  {
    int v = hcnt[tid];
    __shared__ int sc[256];
    sc[tid] = v;
    __syncthreads();
    for (int off = 1; off < 256; off <<= 1) {
      int t = (tid >= off) ? sc[tid - off] : 0;
      __syncthreads();
      sc[tid] += t;
      __syncthreads();
    }
    hstart[tid] = sc[tid] - v;
    if (tid < nbkt && v > 0) gbase[tid] = atomicAdd(&gcur[tid], v);
    hcnt[tid] = sc[tid] - v;  // reset as running cursor
  }
  __syncthreads();

  // scatter into LDS, compacted by bucket
#pragma unroll
  for (int k = 0; k < 16; ++k) {
    if (dArr[k] >= 0) {
      int b = dArr[k] >> shift;
      int p = atomicAdd(&hcnt[b], 1);
      sbuf[p] = ((unsigned long long)(unsigned)dArr[k] << 32) | (unsigned)sArr[k];
    }
  }
  __syncthreads();

  // coalesced copy-out of per-bucket runs
  for (int p = tid; p < validCount; p += 256) {
    unsigned long long v = sbuf[p];
    int b = (int)(v >> 32) >> shift;
    sorted[(size_t)gbase[b] + (p - hstart[b])] = v;
  }
}

// 4) phase B: one block per bucket -> rowptr (via LDS hist+scan) + eidx scatter.
__global__ __launch_bounds__(256) void k_bcsr(
    const unsigned long long* __restrict__ sorted, const int* __restrict__ bbase,
    int* __restrict__ rowptr, int* __restrict__ eidx,
    int shift, int nbkt, int N, int E) {
  __shared__ int cnt[512];
  __shared__ int excl[512];
  __shared__ int sc[256];
  const int b = blockIdx.x, tid = threadIdx.x;
  const int nodeBase = b << shift;
  const int nodesHere = min(512, N - nodeBase);
  const int lo = bbase[b], hi = bbase[b + 1];

  cnt[tid] = 0; cnt[tid + 256] = 0;
  __syncthreads();
  for (int i = lo + tid; i < hi; i += 256) {
    int d = (int)(sorted[i] >> 32);
    atomicAdd(&cnt[d - nodeBase], 1);
  }
  __syncthreads();
  int a0 = cnt[2 * tid], a1 = cnt[2 * tid + 1];
  int pv = a0 + a1;
  sc[tid] = pv;
  __syncthreads();
  for (int off = 1; off < 256; off <<= 1) {
    int t = (tid >= off) ? sc[tid - off] : 0;
    __syncthreads();
    sc[tid] += t;
    __syncthreads();
  }
  int pe = sc[tid] - pv;
  excl[2 * tid] = pe;
  excl[2 * tid + 1] = pe + a0;
  __syncthreads();
  for (int i = tid; i < 512; i += 256) {
    if (i < nodesHere) rowptr[nodeBase + i] = lo + excl[i];
    cnt[i] = excl[i];
  }
  if (b == nbkt - 1 && tid == 0) rowptr[N] = E;
  __syncthreads();
  for (int i = lo + tid; i < hi; i += 256) {
    unsigned long long v = sorted[i];
    int d = (int)(v >> 32);
    int s = (int)(v & 0xFFFFFFFFu);
    int p = atomicAdd(&cnt[d - nodeBase], 1);
    eidx[lo + p] = s;
  }
}

// ================= merged prep: concat0 + weights + pool-init + epilogue params ==========
struct PrepArgs {
  const float *x, *pos;
  const float *w01, *w11, *w21, *w02, *w12, *w22;
  const float *b01, *g01, *e01, *b02, *g02, *e02;
  const float *b11, *g11, *e11, *b12, *g12, *e12;
  const float *b21, *g21, *e21, *b22, *g22, *e22;
  unsigned short *h0;
  unsigned short *Wt;
  unsigned *pooled;
  float *Ep;     // [3][2][2][128]: (sc, c) per layer per stage
  int N, GH;
};

__global__ __launch_bounds__(256) void k_prep(PrepArgs a) {
  const int gtid = blockIdx.x * 256 + threadIdx.x;

  // pool init
  if (gtid < a.GH) a.pooled[gtid] = 0x007FFFFFu;  // enc(-inf)

  // weights: Wt1_l at l*20480 (128 x 160 k-major), Wt2_l at 61440 + l*16384
  if (gtid < 61440) {
    int l = gtid / 20480, rem = gtid % 20480;
    int n = rem / 160, k = rem % 160;
    const float* W = (l == 0) ? a.w01 : ((l == 1) ? a.w11 : a.w21);
    int K = (l == 0) ? 66 : 130;
    float v = (k < K) ? W[(size_t)k * 128 + n] : 0.0f;
    a.Wt[gtid] = f2us(v);
  } else if (gtid < 110592) {
    int idx2 = gtid - 61440;
    int l = idx2 / 16384, rem = idx2 % 16384;
    int n = rem / 128, k = rem % 128;
    const float* W = (l == 0) ? a.w02 : ((l == 1) ? a.w12 : a.w22);
    a.Wt[gtid] = f2us(W[(size_t)k * 128 + n]);
  } else if (gtid < 110592 + 768) {
    // epilogue params: relu((acc+b)*g*BN_INV + e) == relu(acc*sc + c), c = b*sc + e
    int idx = gtid - 110592;
    int col = idx & 127, stage = (idx >> 7) & 1, l = idx >> 8;
    const float *bb, *gg, *ee;
    if (l == 0)      { if (!stage) { bb = a.b01; gg = a.g01; ee = a.e01; } else { bb = a.b02; gg = a.g02; ee = a.e02; } }
    else if (l == 1) { if (!stage) { bb = a.b11; gg = a.g11; ee = a.e11; } else { bb = a.b12; gg = a.g12; ee = a.e12; } }
    else             { if (!stage) { bb = a.b21; gg = a.g21; ee = a.e21; } else { bb = a.b22; gg = a.g22; ee = a.e22; } }
    float s = gg[col] * BN_INV;
    a.Ep[l * 512 + stage * 256 + col] = s;
    a.Ep[l * 512 + stage * 256 + 128 + col] = bb[col] * s + ee[col];
  }

  // concat0 (wave per row): 0..63 = x, 64..65 = pos, 66..127 = 0, 128..129 = pos, 130..135 = 0
  int r = gtid >> 6;
  if (r < a.N) {
    int lane = gtid & 63;
    a.h0[(size_t)r * RB + lane] = f2us(a.x[(size_t)r * 64 + lane]);
    float pv = (lane < 2) ? a.pos[(size_t)r * 2 + lane] : 0.0f;
    a.h0[(size_t)r * RB + 64 + lane] = f2us(pv);
    if (lane < 8) {
      a.h0[(size_t)r * RB + 128 + lane] = f2us((lane < 2) ? a.pos[(size_t)r * 2 + lane] : 0.0f);
    }
  }
}

// ================= neighbor max aggregation (fp16, packed, 4-deep) =================
// z = hcat + max_{src->i} hcat[src]. One wave per node; halves take alternate edges;
// each half keeps 4 gathers in flight. Lane lc covers fp16 cols lc*8..lc*8+7.
__global__ __launch_bounds__(256) void k_agg(
    const unsigned short* __restrict__ hcat, const int* __restrict__ rowptr,
    const int* __restrict__ eidx, unsigned short* __restrict__ z,
    int actA, int doTail, int N) {
  int wid = (int)((blockIdx.x * 256 + threadIdx.x) >> 6);
  if (wid >= N) return;
  const int lane = threadIdx.x & 63;
  const int half = lane >> 5;
  const int lc = lane & 31;
  const bool act = (lc < actA) || (doTail && lc == 16);
  const int cb = lc * 8;   // fp16 col base

  const unsigned NEGINF = 0xFC00FC00u;  // (-inf, -inf) fp16
  unsigned m0 = NEGINF, m1 = NEGINF, m2 = NEGINF, m3 = NEGINF;

  int r0 = rowptr[wid], r1 = rowptr[wid + 1];
  int e = r0 + half;
  for (; e + 6 < r1; e += 8) {   // this half handles e, e+2, e+4, e+6 (4 gathers in flight)
    int s0 = eidx[e], s1 = eidx[e + 2], s2 = eidx[e + 4], s3 = eidx[e + 6];
    if (act) {
      uint4 v0 = *(const uint4*)(hcat + (size_t)s0 * RB + cb);
      uint4 v1 = *(const uint4*)(hcat + (size_t)s1 * RB + cb);
      uint4 v2 = *(const uint4*)(hcat + (size_t)s2 * RB + cb);
      uint4 v3 = *(const uint4*)(hcat + (size_t)s3 * RB + cb);
      m0 = pkmax(m0, pkmax(pkmax(v0.x, v1.x), pkmax(v2.x, v3.x)));
      m1 = pkmax(m1, pkmax(pkmax(v0.y, v1.y), pkmax(v2.y, v3.y)));
      m2 = pkmax(m2, pkmax(pkmax(v0.z, v1.z), pkmax(v2.z, v3.z)));
      m3 = pkmax(m3, pkmax(pkmax(v0.w, v1.w), pkmax(v2.w, v3.w)));
    }
  }
  for (; e < r1; e += 2) {
    int s = eidx[e];
    if (act) {
      uint4 va = *(const uint4*)(hcat + (size_t)s * RB + cb);
      m0 = pkmax(m0, va.x);
      m1 = pkmax(m1, va.y);
      m2 = pkmax(m2, va.z);
      m3 = pkmax(m3, va.w);
    }
  }

  // combine the two halves
  m0 = pkmax(m0, (unsigned)__shfl_xor((int)m0, 32));
  m1 = pkmax(m1, (unsigned)__shfl_xor((int)m1, 32));
  m2 = pkmax(m2, (unsigned)__shfl_xor((int)m2, 32));
  m3 = pkmax(m3, (unsigned)__shfl_xor((int)m3, 32));

  if (half == 0 && act) {
    if (r0 == r1) { m0 = 0u; m1 = 0u; m2 = 0u; m3 = 0u; }  // empty neighborhood -> 0
    uint4 sv = *(const uint4*)(hcat + (size_t)wid * RB + cb);
    uint4 o;
    o.x = pkadd(sv.x, m0);
    o.y = pkadd(sv.y, m1);
    o.z = pkadd(sv.z, m2);
    o.w = pkadd(sv.w, m3);
    *(uint4*)(z + (size_t)wid * RB + cb) = o;
  }
}

// ================= fused MFMA MLP (fp16 in, f32 accum) =================
// Block = 256 = 4 waves; wave w owns rows w*16..+15 (no barriers anywhere).
// z tile staged into LDS coalesced (cols 136..159 zeroed); unwritten z regions are
// finite garbage that only ever multiplies zero-padded Wt1 rows -> no z memset needed.
__global__ __launch_bounds__(256) void k_mlp(
    const unsigned short* __restrict__ z, int kc1,
    const unsigned short* __restrict__ Wt1, const float* __restrict__ Ep1,
    const unsigned short* __restrict__ Wt2, const float* __restrict__ Ep2,
    unsigned short* __restrict__ out, int N) {
  __shared__ __align__(16) unsigned short zs[4][16][ZS];
  const int tid = threadIdx.x;
  const int w = tid >> 6, lane = tid & 63;
  const int arow = lane & 15;   // A row within 16-row tile; also B/D column offset
  const int grp  = lane >> 4;   // k-group (and D row group)
  const int row0 = blockIdx.x * 64 + w * 16;

  // stage this wave's 16 z-rows: 21 x 16B chunks per row (17 real + 4 zero)
  for (int c = lane; c < 16 * 21; c += 64) {
    int r = c / 21, seg = c - r * 21;
    uint4 v = make_uint4(0u, 0u, 0u, 0u);
    if (seg < 17) {
      int gr = row0 + r;
      if (gr >= N) gr = N - 1;   // clamp: reads in-bounds; writes guarded below
      v = *(const uint4*)(z + (size_t)gr * RB + seg * 8);
    }
    *(uint4*)(&zs[w][r][seg * 8]) = v;
  }

  float4v acc[8];
#pragma unroll
  for (int i = 0; i < 8; ++i) acc[i] = (float4v){0.f, 0.f, 0.f, 0.f};

  // ---- GEMM1: kc1*32 wide (zero-padded K; Wt1 stride 160) ----
  for (int kc = 0; kc < kc1; ++kc) {
    half8v a = *(const half8v*)(&zs[w][arow][kc * 32 + grp * 8]);
    const unsigned short* wp = Wt1 + (size_t)arow * 160 + kc * 32 + grp * 8;
#pragma unroll
    for (int nt = 0; nt < 8; ++nt) {
      half8v b = *(const half8v*)(wp + (size_t)(nt * 16) * 160);
      acc[nt] = __builtin_amdgcn_mfma_f32_16x16x32_f16(a, b, acc[nt], 0, 0, 0);
    }
  }

  // ---- epilogue 1 -> h1 overwrites zs (cols 0..127; same-wave producer/consumer) ----
#pragma unroll
  for (int nt = 0; nt < 8; ++nt) {
    int col = nt * 16 + arow;
    float sc = Ep1[col];
    float cc = Ep1[128 + col];
#pragma unroll
    for (int j = 0; j < 4; ++j) {
      float v = fmaxf(fmaf(acc[nt][j], sc, cc), 0.0f);
      zs[w][grp * 4 + j][col] = f2us(v);
    }
  }

  // ---- GEMM2: 128 x 128 ----
#pragma unroll
  for (int i = 0; i < 8; ++i) acc[i] = (float4v){0.f, 0.f, 0.f, 0.f};
  for (int kc = 0; kc < 4; ++kc) {
    half8v a = *(const half8v*)(&zs[w][arow][kc * 32 + grp * 8]);
    const unsigned short* wp = Wt2 + (size_t)arow * HDIM + kc * 32 + grp * 8;
#pragma unroll
    for (int nt = 0; nt < 8; ++nt) {
      half8v b = *(const half8v*)(wp + (size_t)(nt * 16) * HDIM);
      acc[nt] = __builtin_amdgcn_mfma_f32_16x16x32_f16(a, b, acc[nt], 0, 0, 0);
    }
  }

  // ---- epilogue 2 -> global fp16 (cols 0..127) ----
#pragma unroll
  for (int nt = 0; nt < 8; ++nt) {
    int col = nt * 16 + arow;
    float sc = Ep2[col];
    float cc = Ep2[128 + col];
#pragma unroll
    for (int j = 0; j < 4; ++j) {
      int gr = row0 + grp * 4 + j;
      if (gr < N) {
        float v = fmaxf(fmaf(acc[nt][j], sc, cc), 0.0f);
        out[(size_t)gr * RB + col] = f2us(v);
      }
    }
  }
}

// ================= global max pool (batch sorted) =================
__global__ __launch_bounds__(128) void k_pool(
    const unsigned short* __restrict__ hcat, const int* __restrict__ batch,
    unsigned* __restrict__ pooled, int N) {
  int base = blockIdx.x * 128;
  int c = threadIdx.x;
  int end = min(base + 128, N);
  int curg = -1;
  float m = -INFINITY;
  for (int i = base; i < end; ++i) {
    int g = batch[i];
    if (g != curg) {
      if (curg >= 0) atomicMax(&pooled[curg * HDIM + c], encf(m));
      curg = g;
      m = -INFINITY;
    }
    m = fmaxf(m, us2f(hcat[(size_t)i * RB + c]));
  }
  if (curg >= 0) atomicMax(&pooled[curg * HDIM + c], encf(m));
}

// ================= final linear [G,128] @ [128,2] =================
__global__ __launch_bounds__(64) void k_final(
    const unsigned* __restrict__ pooled, const float* __restrict__ wlin,
    const float* __restrict__ blin, float* __restrict__ out) {
  int g = blockIdx.x;
  int lane = threadIdx.x;
  float v0 = decf(pooled[g * HDIM + lane]);
  float v1 = decf(pooled[g * HDIM + 64 + lane]);
  if (v0 == -INFINITY) v0 = 0.0f;  // empty graph -> 0
  if (v1 == -INFINITY) v1 = 0.0f;
  float p0 = v0 * wlin[lane * 2 + 0] + v1 * wlin[(64 + lane) * 2 + 0];
  float p1 = v0 * wlin[lane * 2 + 1] + v1 * wlin[(64 + lane) * 2 + 1];
  for (int off = 32; off > 0; off >>= 1) {
    p0 += __shfl_down(p0, off);
    p1 += __shfl_down(p1, off);
  }
  if (lane == 0) {
    out[g * 2 + 0] = p0 + blin[0];
    out[g * 2 + 1] = p1 + blin[1];
  }
}

// ================= host launcher =================
static inline size_t ws_align(size_t x) { return (x + 511) & ~(size_t)511; }

extern "C" void kernel_launch(void* const* d_in, const int* in_sizes, int n_in,
                              void* d_out, int out_size, void* d_ws, size_t ws_size,
                              hipStream_t stream) {
  const float* x     = (const float*)d_in[0];
  const float* pos   = (const float*)d_in[1];
  const int*   ei    = (const int*)d_in[2];
  const int*   batch = (const int*)d_in[3];
  const float* wlin  = (const float*)d_in[28];
  const float* blin  = (const float*)d_in[29];

  const int N = in_sizes[3];          // batch has N elements
  const int E = in_sizes[2] / 2;
  const int G = out_size / 2;

  // bucket geometry: <=256 buckets of 2^shift nodes (bcsr assumes <=512 nodes/bucket)
  int shift = 9;
  while ((((N - 1) >> shift) + 1) > 256) ++shift;
  const int nbkt = ((N - 1) >> shift) + 1;
  const int chunks = (E + 4095) / 4096;

  // workspace layout
  char* w = (char*)d_ws;
  size_t off = 0;
  auto take = [&](size_t bytes) { void* p = w + off; off += ws_align(bytes); return p; };
  int*            rowptr    = (int*)take((size_t)(N + 1) * 4);
  int*            chunkHist = (int*)take((size_t)chunks * 256 * 4);
  int*            bbase     = (int*)take(2048);
  int*            gcur      = (int*)take(1024);
  int*            eidx      = (int*)take((size_t)E * 4);
  unsigned long long* sorted = (unsigned long long*)take((size_t)E * 8);
  unsigned short* hcat      = (unsigned short*)take((size_t)N * RB * 2 + 1024);
  unsigned short* z         = (unsigned short*)take((size_t)N * RB * 2 + 1024);
  unsigned short* Wt        = (unsigned short*)take((size_t)110592 * 2);
  float*          Ep        = (float*)take(3 * 2 * 2 * 128 * 4);
  unsigned*       pooled    = (unsigned*)take((size_t)G * HDIM * 4);
  (void)ws_size;

  // ---- build CSR by dst (bucketed, all cursors in LDS, zero memsets) ----
  k_bcnt<<<chunks, 256, 0, stream>>>(ei, chunkHist, E, shift);
  k_bscan<<<1, 256, 0, stream>>>(chunkHist, chunks, bbase, gcur, nbkt, E);
  k_bscatter<<<chunks, 256, 0, stream>>>(ei, gcur, sorted, E, shift, nbkt);
  k_bcsr<<<nbkt, 256, 0, stream>>>(sorted, bbase, rowptr, eidx, shift, nbkt, N, E);

  // ---- merged prep (concat0 + weights + epilogue params + pool init) ----
  {
    PrepArgs a;
    a.x = x; a.pos = pos;
    a.w01 = (const float*)d_in[4];  a.w11 = (const float*)d_in[12]; a.w21 = (const float*)d_in[20];
    a.w02 = (const float*)d_in[8];  a.w12 = (const float*)d_in[16]; a.w22 = (const float*)d_in[24];
    a.b01 = (const float*)d_in[5];  a.g01 = (const float*)d_in[6];  a.e01 = (const float*)d_in[7];
    a.b02 = (const float*)d_in[9];  a.g02 = (const float*)d_in[10]; a.e02 = (const float*)d_in[11];
    a.b11 = (const float*)d_in[13]; a.g11 = (const float*)d_in[14]; a.e11 = (const float*)d_in[15];
    a.b12 = (const float*)d_in[17]; a.g12 = (const float*)d_in[18]; a.e12 = (const float*)d_in[19];
    a.b21 = (const float*)d_in[21]; a.g21 = (const float*)d_in[22]; a.e21 = (const float*)d_in[23];
    a.b22 = (const float*)d_in[25]; a.g22 = (const float*)d_in[26]; a.e22 = (const float*)d_in[27];
    a.h0 = hcat; a.Wt = Wt; a.pooled = pooled; a.Ep = Ep;
    a.N = N; a.GH = G * HDIM;
    k_prep<<<(N + 3) / 4, 256, 0, stream>>>(a);
  }

  // layer 0: gather cols 0..71 (K=66); layer 1: + tail 128..135 (pos+maxpos);
  // layer 2: z[128..135] reused from layer 1 (layer-invariant).
  const int actA[3]   = {9, 16, 16};
  const int doTail[3] = {0, 1, 0};
  const int kc1a[3]   = {3, 5, 5};
  const int aggBlocks = (N + 3) / 4;
  const int mlpBlocks = (N + 63) / 64;

  for (int l = 0; l < 3; ++l) {
    const unsigned short* Wt1 = Wt + (size_t)l * 20480;
    const unsigned short* Wt2 = Wt + 61440 + (size_t)l * 16384;
    const float* Ep1 = Ep + l * 512;
    const float* Ep2 = Ep + l * 512 + 256;

    k_agg<<<aggBlocks, 256, 0, stream>>>(hcat, rowptr, eidx, z, actA[l], doTail[l], N);
    k_mlp<<<mlpBlocks, 256, 0, stream>>>(z, kc1a[l], Wt1, Ep1, Wt2, Ep2, hcat, N);
  }

  // ---- pool + final linear ----
  k_pool<<<(N + 127) / 128, 128, 0, stream>>>(hcat, batch, pooled, N);
  k_final<<<G, 64, 0, stream>>>(pooled, wlin, blin, (float*)d_out);
}

// Round 11
// 518.604 us; speedup vs baseline: 1.0808x; 1.0808x over previous
//
#include <hip/hip_runtime.h>
#include <hip/hip_fp16.h>
#include <math.h>
#include <string.h>

// ---------------- constants ----------------
constexpr int HDIM = 128;     // hidden width; hcat row stride (256B = 4 aligned lines)
constexpr int ZR   = 160;     // z row stride fp16 (320B, line-aligned)
constexpr int ZS   = 168;     // LDS z-tile stride (336B -> 2-way banks for b128 reads)
constexpr float BN_INV = 0.99999500003749980f; // 1/sqrt(1+1e-5)

typedef _Float16 half8v __attribute__((ext_vector_type(8)));  // 8 fp16 (4 VGPR)
typedef __attribute__((ext_vector_type(4))) float float4v;    // MFMA accum

// packed fp16 ops on raw u32 pairs (VOP3P)
__device__ __forceinline__ unsigned pkmax(unsigned a, unsigned b) {
  unsigned r;
  asm volatile("v_pk_max_f16 %0, %1, %2" : "=v"(r) : "v"(a), "v"(b));
  return r;
}
__device__ __forceinline__ unsigned pkadd(unsigned a, unsigned b) {
  unsigned r;
  asm volatile("v_pk_add_f16 %0, %1, %2" : "=v"(r) : "v"(a), "v"(b));
  return r;
}

__device__ __forceinline__ float us2f(unsigned short u) { __half h; memcpy(&h, &u, 2); return __half2float(h); }
__device__ __forceinline__ unsigned short f2us(float f) {
  __half h = __float2half(f); unsigned short u; memcpy(&u, &h, 2); return u;
}

// monotone float<->uint encoding for atomic max on floats
__device__ __forceinline__ unsigned encf(float f) {
  unsigned u = __float_as_uint(f);
  return (u & 0x80000000u) ? ~u : (u | 0x80000000u);
}
__device__ __forceinline__ float decf(unsigned u) {
  return (u & 0x80000000u) ? __uint_as_float(u ^ 0x80000000u) : __uint_as_float(~u);
}

// ================= CSR build (bucket-local, LDS-atomic) =================
// 1) bucket histogram (LDS-staged, global atomic flush) -- R9 proven form
__global__ __launch_bounds__(256) void k_bcnt(
    const int* __restrict__ ei, int* __restrict__ bcnt, int E, int shift, int nbkt) {
  __shared__ int hb[256];
  const int tid = threadIdx.x;
  hb[tid] = 0;
  __syncthreads();
  const int base = blockIdx.x * 4096;
#pragma unroll
  for (int k = 0; k < 16; ++k) {
    int e = base + k * 256 + tid;
    if (e < E) atomicAdd(&hb[ei[E + e] >> shift], 1);
  }
  __syncthreads();
  if (tid < nbkt && hb[tid] > 0) atomicAdd(&bcnt[tid], hb[tid]);
}

// 2) bucket exclusive scan -> bbase[0..nbkt], gcur
__global__ __launch_bounds__(256) void k_bscan(
    const int* __restrict__ bcnt, int* __restrict__ bbase, int* __restrict__ gcur,
    int nbkt, int E) {
  __shared__ int s[256];
  int tid = threadIdx.x;
  int v = (tid < nbkt) ? bcnt[tid] : 0;
  s[tid] = v;
  __syncthreads();
  for (int off = 1; off < 256; off <<= 1) {
    int t = (tid >= off) ? s[tid - off] : 0;
    __syncthreads();
    s[tid] += t;
    __syncthreads();
  }
  if (tid < nbkt) {
    int e = s[tid] - v;
    bbase[tid] = e;
    gcur[tid] = e;
  }
  if (tid == 0) bbase[nbkt] = E;
}

// 3) phase A: block-local LDS counting-sort of 4096-edge chunks by bucket,
//    run-coalesced flush into per-bucket regions of `sorted` (u64 = dst<<32 | src)
__global__ __launch_bounds__(256) void k_bscatter(
    const int* __restrict__ ei, int* __restrict__ gcur,
    unsigned long long* __restrict__ sorted, int E, int shift, int nbkt) {
  __shared__ int hcnt[256];   // per-bucket count, then reused as cursor
  __shared__ int hstart[256]; // exclusive start within chunk
  __shared__ int gbase[256];  // global base for this block's run
  __shared__ unsigned long long sbuf[4096];  // 32 KB

  const int tid = threadIdx.x;
  const int base = blockIdx.x * 4096;
  const int validCount = min(4096, E - base);

  hcnt[tid] = 0;
  __syncthreads();

  int sArr[16], dArr[16];
#pragma unroll
  for (int k = 0; k < 16; ++k) {
    int e = base + k * 256 + tid;
    if (e < E) {
      sArr[k] = ei[e];
      dArr[k] = ei[E + e];
      atomicAdd(&hcnt[dArr[k] >> shift], 1);
    } else {
      sArr[k] = -1; dArr[k] = -1;
    }
  }
  __syncthreads();

  // exclusive scan of hcnt into hstart
  {
    int v = hcnt[tid];
    __shared__ int sc[256];
    sc[tid] = v;
    __syncthreads();
    for (int off = 1; off < 256; off <<= 1) {
      int t = (tid >= off) ? sc[tid - off] : 0;
      __syncthreads();
      sc[tid] += t;
      __syncthreads();
    }
    hstart[tid] = sc[tid] - v;
    if (tid < nbkt && v > 0) gbase[tid] = atomicAdd(&gcur[tid], v);
    hcnt[tid] = sc[tid] - v;  // reset as running cursor
  }
  __syncthreads();

  // scatter into LDS, compacted by bucket
#pragma unroll
  for (int k = 0; k < 16; ++k) {
    if (dArr[k] >= 0) {
      int b = dArr[k] >> shift;
      int p = atomicAdd(&hcnt[b], 1);
      sbuf[p] = ((unsigned long long)(unsigned)dArr[k] << 32) | (unsigned)sArr[k];
    }
  }
  __syncthreads();

  // coalesced copy-out of per-bucket runs
  for (int p = tid; p < validCount; p += 256) {
    unsigned long long v = sbuf[p];
    int b = (int)(v >> 32) >> shift;
    sorted[(size_t)gbase[b] + (p - hstart[b])] = v;
  }
}

// 4) phase B: one block per bucket -> rowptr (via LDS hist+scan) + eidx scatter.
__global__ __launch_bounds__(256) void k_bcsr(
    const unsigned long long* __restrict__ sorted, const int* __restrict__ bbase,
    int* __restrict__ rowptr, int* __restrict__ eidx,
    int shift, int nbkt, int N, int E) {
  __shared__ int cnt[512];
  __shared__ int excl[512];
  __shared__ int sc[256];
  const int b = blockIdx.x, tid = threadIdx.x;
  const int nodeBase = b << shift;
  const int nodesHere = min(512, N - nodeBase);
  const int lo = bbase[b], hi = bbase[b + 1];

  cnt[tid] = 0; cnt[tid + 256] = 0;
  __syncthreads();
  for (int i = lo + tid; i < hi; i += 256) {
    int d = (int)(sorted[i] >> 32);
    atomicAdd(&cnt[d - nodeBase], 1);
  }
  __syncthreads();
  int a0 = cnt[2 * tid], a1 = cnt[2 * tid + 1];
  int pv = a0 + a1;
  sc[tid] = pv;
  __syncthreads();
  for (int off = 1; off < 256; off <<= 1) {
    int t = (tid >= off) ? sc[tid - off] : 0;
    __syncthreads();
    sc[tid] += t;
    __syncthreads();
  }
  int pe = sc[tid] - pv;
  excl[2 * tid] = pe;
  excl[2 * tid + 1] = pe + a0;
  __syncthreads();
  for (int i = tid; i < 512; i += 256) {
    if (i < nodesHere) rowptr[nodeBase + i] = lo + excl[i];
    cnt[i] = excl[i];
  }
  if (b == nbkt - 1 && tid == 0) rowptr[N] = E;
  __syncthreads();
  for (int i = lo + tid; i < hi; i += 256) {
    unsigned long long v = sorted[i];
    int d = (int)(v >> 32);
    int s = (int)(v & 0xFFFFFFFFu);
    int p = atomicAdd(&cnt[d - nodeBase], 1);
    eidx[lo + p] = s;
  }
}

// ================= merged prep: concat0 + posq + weights + pool-init + epilogue params ====
struct PrepArgs {
  const float *x, *pos;
  const float *w01, *w11, *w21, *w02, *w12, *w22;
  const float *b01, *g01, *e01, *b02, *g02, *e02;
  const float *b11, *g11, *e11, *b12, *g12, *e12;
  const float *b21, *g21, *e21, *b22, *g22, *e22;
  unsigned short *h0;    // [N][128]
  unsigned *posq;        // [N] packed 2 x fp16 pos
  unsigned short *Wt;
  unsigned *pooled;
  float *Ep;             // [3][2][2][128]: (sc, c) per layer per stage
  int N, GH;
};

__global__ __launch_bounds__(256) void k_prep(PrepArgs a) {
  const int gtid = blockIdx.x * 256 + threadIdx.x;

  // pool init
  if (gtid < a.GH) a.pooled[gtid] = 0x007FFFFFu;  // enc(-inf)

  // weights: Wt1_l at l*20480 (128 x 160 k-major), Wt2_l at 61440 + l*16384
  if (gtid < 61440) {
    int l = gtid / 20480, rem = gtid % 20480;
    int n = rem / 160, k = rem % 160;
    const float* W = (l == 0) ? a.w01 : ((l == 1) ? a.w11 : a.w21);
    int K = (l == 0) ? 66 : 130;
    float v = (k < K) ? W[(size_t)k * 128 + n] : 0.0f;
    a.Wt[gtid] = f2us(v);
  } else if (gtid < 110592) {
    int idx2 = gtid - 61440;
    int l = idx2 / 16384, rem = idx2 % 16384;
    int n = rem / 128, k = rem % 128;
    const float* W = (l == 0) ? a.w02 : ((l == 1) ? a.w12 : a.w22);
    a.Wt[gtid] = f2us(W[(size_t)k * 128 + n]);
  } else if (gtid < 110592 + 768) {
    // relu((acc+b)*g*BN_INV + e) == relu(acc*sc + c), c = b*sc + e
    int idx = gtid - 110592;
    int col = idx & 127, stage = (idx >> 7) & 1, l = idx >> 8;
    const float *bb, *gg, *ee;
    if (l == 0)      { if (!stage) { bb = a.b01; gg = a.g01; ee = a.e01; } else { bb = a.b02; gg = a.g02; ee = a.e02; } }
    else if (l == 1) { if (!stage) { bb = a.b11; gg = a.g11; ee = a.e11; } else { bb = a.b12; gg = a.g12; ee = a.e12; } }
    else             { if (!stage) { bb = a.b21; gg = a.g21; ee = a.e21; } else { bb = a.b22; gg = a.g22; ee = a.e22; } }
    float s = gg[col] * BN_INV;
    a.Ep[l * 512 + stage * 256 + col] = s;
    a.Ep[l * 512 + stage * 256 + 128 + col] = bb[col] * s + ee[col];
  }

  // concat0 (wave per row): hcat[r] = [x(64) | pos(2) | zeros(62)]; posq[r] = packed pos
  int r = gtid >> 6;
  if (r < a.N) {
    int lane = gtid & 63;
    a.h0[(size_t)r * HDIM + lane] = f2us(a.x[(size_t)r * 64 + lane]);
    float pv = (lane < 2) ? a.pos[(size_t)r * 2 + lane] : 0.0f;
    a.h0[(size_t)r * HDIM + 64 + lane] = f2us(pv);
    if (lane == 0) {
      unsigned p2 = (unsigned)f2us(a.pos[(size_t)r * 2]) |
                    ((unsigned)f2us(a.pos[(size_t)r * 2 + 1]) << 16);
      a.posq[r] = p2;
    }
  }
}

// ================= neighbor max aggregation (fp16, packed, 4-deep) =================
// z[0..127] = hcat + max(hcat[src]); z[128..129] = pos + max(pos[src]) (layer 1 only;
// layer 2 reuses it). hcat rows are 256B = exactly 4 aligned cache lines.
// posq (400KB) is L2-resident -> tail gather ~free.
__global__ __launch_bounds__(256) void k_agg(
    const unsigned short* __restrict__ hcat, const unsigned* __restrict__ posq,
    const int* __restrict__ rowptr, const int* __restrict__ eidx,
    unsigned short* __restrict__ z, int actA, int doTail, int N) {
  int wid = (int)((blockIdx.x * 256 + threadIdx.x) >> 6);
  if (wid >= N) return;
  const int lane = threadIdx.x & 63;
  const int half = lane >> 5;
  const int lc = lane & 31;
  const bool act = lc < actA;
  const bool tail = doTail && (lc == 16);
  const int cb = lc * 8;   // fp16 col base

  const unsigned NEGINF = 0xFC00FC00u;  // (-inf, -inf) fp16
  unsigned m0 = NEGINF, m1 = NEGINF, m2 = NEGINF, m3 = NEGINF, mt = NEGINF;

  int r0 = rowptr[wid], r1 = rowptr[wid + 1];
  int e = r0 + half;
  for (; e + 6 < r1; e += 8) {   // this half handles e, e+2, e+4, e+6 (4 gathers in flight)
    int s0 = eidx[e], s1 = eidx[e + 2], s2 = eidx[e + 4], s3 = eidx[e + 6];
    if (act) {
      uint4 v0 = *(const uint4*)(hcat + (size_t)s0 * HDIM + cb);
      uint4 v1 = *(const uint4*)(hcat + (size_t)s1 * HDIM + cb);
      uint4 v2 = *(const uint4*)(hcat + (size_t)s2 * HDIM + cb);
      uint4 v3 = *(const uint4*)(hcat + (size_t)s3 * HDIM + cb);
      m0 = pkmax(m0, pkmax(pkmax(v0.x, v1.x), pkmax(v2.x, v3.x)));
      m1 = pkmax(m1, pkmax(pkmax(v0.y, v1.y), pkmax(v2.y, v3.y)));
      m2 = pkmax(m2, pkmax(pkmax(v0.z, v1.z), pkmax(v2.z, v3.z)));
      m3 = pkmax(m3, pkmax(pkmax(v0.w, v1.w), pkmax(v2.w, v3.w)));
    }
    if (tail) {
      mt = pkmax(mt, pkmax(pkmax(posq[s0], posq[s1]), pkmax(posq[s2], posq[s3])));
    }
  }
  for (; e < r1; e += 2) {
    int s = eidx[e];
    if (act) {
      uint4 va = *(const uint4*)(hcat + (size_t)s * HDIM + cb);
      m0 = pkmax(m0, va.x);
      m1 = pkmax(m1, va.y);
      m2 = pkmax(m2, va.z);
      m3 = pkmax(m3, va.w);
    }
    if (tail) mt = pkmax(mt, posq[s]);
  }

  // combine the two halves
  m0 = pkmax(m0, (unsigned)__shfl_xor((int)m0, 32));
  m1 = pkmax(m1, (unsigned)__shfl_xor((int)m1, 32));
  m2 = pkmax(m2, (unsigned)__shfl_xor((int)m2, 32));
  m3 = pkmax(m3, (unsigned)__shfl_xor((int)m3, 32));
  mt = pkmax(mt, (unsigned)__shfl_xor((int)mt, 32));

  if (half == 0) {
    const bool none = (r0 == r1);   // empty neighborhood -> agg 0
    if (act) {
      if (none) { m0 = 0u; m1 = 0u; m2 = 0u; m3 = 0u; }
      uint4 sv = *(const uint4*)(hcat + (size_t)wid * HDIM + cb);
      uint4 o;
      o.x = pkadd(sv.x, m0);
      o.y = pkadd(sv.y, m1);
      o.z = pkadd(sv.z, m2);
      o.w = pkadd(sv.w, m3);
      *(uint4*)(z + (size_t)wid * ZR + cb) = o;
    }
    if (tail) {
      if (none) mt = 0u;
      *(unsigned*)(z + (size_t)wid * ZR + 128) = pkadd(posq[wid], mt);
    }
  }
}

// ================= fused MFMA MLP (fp16 in, f32 accum) =================
// Block = 256 = 4 waves; wave w owns rows w*16..+15 (no barriers anywhere).
// z (stride 160 = 20 x 16B) staged coalesced into LDS; unwritten z cols only ever
// multiply zero-padded Wt1 rows -> no zeroing needed. h1 overwrites the same tile.
__global__ __launch_bounds__(256) void k_mlp(
    const unsigned short* __restrict__ z, int kc1,
    const unsigned short* __restrict__ Wt1, const float* __restrict__ Ep1,
    const unsigned short* __restrict__ Wt2, const float* __restrict__ Ep2,
    unsigned short* __restrict__ out, int N) {
  __shared__ __align__(16) unsigned short zs[4][16][ZS];
  const int tid = threadIdx.x;
  const int w = tid >> 6, lane = tid & 63;
  const int arow = lane & 15;   // A row within 16-row tile; also B/D column offset
  const int grp  = lane >> 4;   // k-group (and D row group)
  const int row0 = blockIdx.x * 64 + w * 16;

  // stage this wave's 16 z-rows: 20 x 16B chunks per row
  for (int c = lane; c < 16 * 20; c += 64) {
    int r = c / 20, seg = c - r * 20;
    int gr = row0 + r;
    if (gr >= N) gr = N - 1;   // clamp: reads in-bounds; writes guarded below
    uint4 v = *(const uint4*)(z + (size_t)gr * ZR + seg * 8);
    *(uint4*)(&zs[w][r][seg * 8]) = v;
  }

  float4v acc[8];
#pragma unroll
  for (int i = 0; i < 8; ++i) acc[i] = (float4v){0.f, 0.f, 0.f, 0.f};

  // ---- GEMM1: kc1*32 wide (zero-padded K; Wt1 stride 160) ----
  for (int kc = 0; kc < kc1; ++kc) {
    half8v a = *(const half8v*)(&zs[w][arow][kc * 32 + grp * 8]);
    const unsigned short* wp = Wt1 + (size_t)arow * 160 + kc * 32 + grp * 8;
#pragma unroll
    for (int nt = 0; nt < 8; ++nt) {
      half8v b = *(const half8v*)(wp + (size_t)(nt * 16) * 160);
      acc[nt] = __builtin_amdgcn_mfma_f32_16x16x32_f16(a, b, acc[nt], 0, 0, 0);
    }
  }

  // ---- epilogue 1 -> h1 overwrites zs (cols 0..127; same-wave producer/consumer) ----
#pragma unroll
  for (int nt = 0; nt < 8; ++nt) {
    int col = nt * 16 + arow;
    float sc = Ep1[col];
    float cc = Ep1[128 + col];
#pragma unroll
    for (int j = 0; j < 4; ++j) {
      float v = fmaxf(fmaf(acc[nt][j], sc, cc), 0.0f);
      zs[w][grp * 4 + j][col] = f2us(v);
    }
  }

  // ---- GEMM2: 128 x 128 ----
#pragma unroll
  for (int i = 0; i < 8; ++i) acc[i] = (float4v){0.f, 0.f, 0.f, 0.f};
  for (int kc = 0; kc < 4; ++kc) {
    half8v a = *(const half8v*)(&zs[w][arow][kc * 32 + grp * 8]);
    const unsigned short* wp = Wt2 + (size_t)arow * HDIM + kc * 32 + grp * 8;
#pragma unroll
    for (int nt = 0; nt < 8; ++nt) {
      half8v b = *(const half8v*)(wp + (size_t)(nt * 16) * HDIM);
      acc[nt] = __builtin_amdgcn_mfma_f32_16x16x32_f16(a, b, acc[nt], 0, 0, 0);
    }
  }

  // ---- epilogue 2 -> global fp16 (hcat stride 128) ----
#pragma unroll
  for (int nt = 0; nt < 8; ++nt) {
    int col = nt * 16 + arow;
    float sc = Ep2[col];
    float cc = Ep2[128 + col];
#pragma unroll
    for (int j = 0; j < 4; ++j) {
      int gr = row0 + grp * 4 + j;
      if (gr < N) {
        float v = fmaxf(fmaf(acc[nt][j], sc, cc), 0.0f);
        out[(size_t)gr * HDIM + col] = f2us(v);
      }
    }
  }
}

// ================= global max pool (batch sorted) =================
__global__ __launch_bounds__(128) void k_pool(
    const unsigned short* __restrict__ hcat, const int* __restrict__ batch,
    unsigned* __restrict__ pooled, int N) {
  int base = blockIdx.x * 128;
  int c = threadIdx.x;
  int end = min(base + 128, N);
  int curg = -1;
  float m = -INFINITY;
  for (int i = base; i < end; ++i) {
    int g = batch[i];
    if (g != curg) {
      if (curg >= 0) atomicMax(&pooled[curg * HDIM + c], encf(m));
      curg = g;
      m = -INFINITY;
    }
    m = fmaxf(m, us2f(hcat[(size_t)i * HDIM + c]));
  }
  if (curg >= 0) atomicMax(&pooled[curg * HDIM + c], encf(m));
}

// ================= final linear [G,128] @ [128,2] =================
__global__ __launch_bounds__(64) void k_final(
    const unsigned* __restrict__ pooled, const float* __restrict__ wlin,
    const float* __restrict__ blin, float* __restrict__ out) {
  int g = blockIdx.x;
  int lane = threadIdx.x;
  float v0 = decf(pooled[g * HDIM + lane]);
  float v1 = decf(pooled[g * HDIM + 64 + lane]);
  if (v0 == -INFINITY) v0 = 0.0f;  // empty graph -> 0
  if (v1 == -INFINITY) v1 = 0.0f;
  float p0 = v0 * wlin[lane * 2 + 0] + v1 * wlin[(64 + lane) * 2 + 0];
  float p1 = v0 * wlin[lane * 2 + 1] + v1 * wlin[(64 + lane) * 2 + 1];
  for (int off = 32; off > 0; off >>= 1) {
    p0 += __shfl_down(p0, off);
    p1 += __shfl_down(p1, off);
  }
  if (lane == 0) {
    out[g * 2 + 0] = p0 + blin[0];
    out[g * 2 + 1] = p1 + blin[1];
  }
}

// ================= host launcher =================
static inline size_t ws_align(size_t x) { return (x + 511) & ~(size_t)511; }

extern "C" void kernel_launch(void* const* d_in, const int* in_sizes, int n_in,
                              void* d_out, int out_size, void* d_ws, size_t ws_size,
                              hipStream_t stream) {
  const float* x     = (const float*)d_in[0];
  const float* pos   = (const float*)d_in[1];
  const int*   ei    = (const int*)d_in[2];
  const int*   batch = (const int*)d_in[3];
  const float* wlin  = (const float*)d_in[28];
  const float* blin  = (const float*)d_in[29];

  const int N = in_sizes[3];          // batch has N elements
  const int E = in_sizes[2] / 2;
  const int G = out_size / 2;

  // bucket geometry: <=256 buckets of 2^shift nodes (bcsr assumes <=512 nodes/bucket)
  int shift = 9;
  while ((((N - 1) >> shift) + 1) > 256) ++shift;
  const int nbkt = ((N - 1) >> shift) + 1;
  const int chunks = (E + 4095) / 4096;

  // workspace layout
  char* w = (char*)d_ws;
  size_t off = 0;
  auto take = [&](size_t bytes) { void* p = w + off; off += ws_align(bytes); return p; };
  int*            rowptr = (int*)take((size_t)(N + 1) * 4);
  int*            bcnt   = (int*)take(1024);
  int*            bbase  = (int*)take(2048);
  int*            gcur   = (int*)take(1024);
  int*            eidx   = (int*)take((size_t)E * 4);
  unsigned long long* sorted = (unsigned long long*)take((size_t)E * 8);
  unsigned short* hcat   = (unsigned short*)take((size_t)N * HDIM * 2);
  unsigned*       posq   = (unsigned*)take((size_t)N * 4);
  unsigned short* z      = (unsigned short*)take((size_t)N * ZR * 2);
  unsigned short* Wt     = (unsigned short*)take((size_t)110592 * 2);
  float*          Ep     = (float*)take(3 * 2 * 2 * 128 * 4);
  unsigned*       pooled = (unsigned*)take((size_t)G * HDIM * 4);
  (void)ws_size;

  // ---- build CSR by dst (bucketed, cursors in LDS) ----
  hipMemsetAsync(bcnt, 0, 1024, stream);
  k_bcnt<<<chunks, 256, 0, stream>>>(ei, bcnt, E, shift, nbkt);
  k_bscan<<<1, 256, 0, stream>>>(bcnt, bbase, gcur, nbkt, E);
  k_bscatter<<<chunks, 256, 0, stream>>>(ei, gcur, sorted, E, shift, nbkt);
  k_bcsr<<<nbkt, 256, 0, stream>>>(sorted, bbase, rowptr, eidx, shift, nbkt, N, E);

  // ---- merged prep (concat0 + posq + weights + epilogue params + pool init) ----
  {
    PrepArgs a;
    a.x = x; a.pos = pos;
    a.w01 = (const float*)d_in[4];  a.w11 = (const float*)d_in[12]; a.w21 = (const float*)d_in[20];
    a.w02 = (const float*)d_in[8];  a.w12 = (const float*)d_in[16]; a.w22 = (const float*)d_in[24];
    a.b01 = (const float*)d_in[5];  a.g01 = (const float*)d_in[6];  a.e01 = (const float*)d_in[7];
    a.b02 = (const float*)d_in[9];  a.g02 = (const float*)d_in[10]; a.e02 = (const float*)d_in[11];
    a.b11 = (const float*)d_in[13]; a.g11 = (const float*)d_in[14]; a.e11 = (const float*)d_in[15];
    a.b12 = (const float*)d_in[17]; a.g12 = (const float*)d_in[18]; a.e12 = (const float*)d_in[19];
    a.b21 = (const float*)d_in[21]; a.g21 = (const float*)d_in[22]; a.e21 = (const float*)d_in[23];
    a.b22 = (const float*)d_in[25]; a.g22 = (const float*)d_in[26]; a.e22 = (const float*)d_in[27];
    a.h0 = hcat; a.posq = posq; a.Wt = Wt; a.pooled = pooled; a.Ep = Ep;
    a.N = N; a.GH = G * HDIM;
    k_prep<<<(N + 3) / 4, 256, 0, stream>>>(a);
  }

  // layer 0: gather cols 0..71 (K=66). layer 1: + posq tail -> z[128..129].
  // layer 2: z[128..129] reused from layer 1 (pos is layer-invariant).
  const int actA[3]   = {9, 16, 16};
  const int doTail[3] = {0, 1, 0};
  const int kc1a[3]   = {3, 5, 5};
  const int aggBlocks = (N + 3) / 4;
  const int mlpBlocks = (N + 63) / 64;

  for (int l = 0; l < 3; ++l) {
    const unsigned short* Wt1 = Wt + (size_t)l * 20480;
    const unsigned short* Wt2 = Wt + 61440 + (size_t)l * 16384;
    const float* Ep1 = Ep + l * 512;
    const float* Ep2 = Ep + l * 512 + 256;

    k_agg<<<aggBlocks, 256, 0, stream>>>(hcat, posq, rowptr, eidx, z,
                                         actA[l], doTail[l], N);
    k_mlp<<<mlpBlocks, 256, 0, stream>>>(z, kc1a[l], Wt1, Ep1, Wt2, Ep2, hcat, N);
  }

  // ---- pool + final linear ----
  k_pool<<<(N + 127) / 128, 128, 0, stream>>>(hcat, batch, pooled, N);
  k_final<<<G, 64, 0, stream>>>(pooled, wlin, blin, (float*)d_out);
}